// Round 3
// baseline (2238.017 us; speedup 1.0000x reference)
//
#include <hip/hip_runtime.h>
#include <stdint.h>

#define TT 400
#define BB 256
#define II 256
#define HH 512
#define NG 2048  // 4*H

typedef __attribute__((ext_vector_type(8))) _Float16 half8;
typedef __attribute__((ext_vector_type(4))) float f32x4;
typedef __attribute__((ext_vector_type(4))) unsigned int u32x4;
typedef unsigned int u32;
typedef unsigned short u16;

static __device__ __forceinline__ u32 f2hbits(float f){
  union { _Float16 h; u16 u; } c; c.h = (_Float16)f; return (u32)c.u;
}

#define GLOAD16(gsrc, ldst) \
  __builtin_amdgcn_global_load_lds((const __attribute__((address_space(1))) void*)(gsrc), \
                                   (__attribute__((address_space(3))) void*)(ldst), 16, 0, 0)

// ---------------------------------------------------------------------------
// Transpose x[B][I][T] fp32 -> xT[t][b][i] fp16. Tile 32(i) x 16(t).
__global__ __launch_bounds__(256) void k_prep_x(const float* __restrict__ x,
                                                u16* __restrict__ xT){
  __shared__ float tile[32][17];
  const int bid = blockIdx.x;
  const int tb = bid % 25, ib = (bid / 25) & 7, b = bid / 200;
  const int t0 = tb * 16, i0 = ib * 32;
  const int tl = threadIdx.x & 15, il = threadIdx.x >> 4;
  tile[il][tl]      = x[(size_t)(b * II + i0 + il) * TT + t0 + tl];
  tile[il + 16][tl] = x[(size_t)(b * II + i0 + il + 16) * TT + t0 + tl];
  __syncthreads();
  const int t_l = threadIdx.x >> 4, ip = threadIdx.x & 15;
  const u32 pack = f2hbits(tile[2 * ip][t_l]) | (f2hbits(tile[2 * ip + 1][t_l]) << 16);
  *(u32*)(xT + ((size_t)(t0 + t_l) * BB + b) * II + i0 + 2 * ip) = pack;
}

// ---------------------------------------------------------------------------
// w_ih[2048][256] fp32 -> fp16.
__global__ __launch_bounds__(256) void k_prep_w(const float* __restrict__ w_ih,
                                                u16* __restrict__ Wp){
  const size_t idx = (size_t)blockIdx.x * 256 + threadIdx.x;  // 0..131071
  const float4 v = *(const float4*)(w_ih + idx * 4);
  uint2 o;
  o.x = f2hbits(v.x) | (f2hbits(v.y) << 16);
  o.y = f2hbits(v.z) | (f2hbits(v.w) << 16);
  *(uint2*)(Wp + idx * 4) = o;
}

// ---------------------------------------------------------------------------
// xg[M=102400][2048] fp16 = A[M][256] @ Wp[2048][256]^T, fp16 MFMA, K=256.
__global__ __launch_bounds__(256) void k_gemm_xg(const u16* __restrict__ A,
                                                 const u16* __restrict__ B,
                                                 _Float16* __restrict__ xg){
  __shared__ char lds[65536];  // A: buf*16384 ; B: 32768 + buf*16384
  const int tid = threadIdx.x, w = tid >> 6, lane = tid & 63;
  const int nb = blockIdx.x & 15, mb = blockIdx.x >> 4;
  const size_t m0 = (size_t)mb * 128;
  const int n0 = nb * 128;
  const int lr = lane & 15, lh = lane >> 4;

  auto stage = [&](int it, int buf){
    const size_t kb = (size_t)it * 128;  // 64 fp16 per k-step
    #pragma unroll
    for (int i2 = 0; i2 < 4; ++i2){
      const int u = w * 256 + i2 * 64 + lane;
      const int r = u >> 3, s = u & 7;
      const char* g = (const char*)A + (m0 + r) * 512 + kb + ((s ^ (r & 7)) << 4);
      char* l = lds + buf * 16384 + ((w * 256 + i2 * 64) << 4);
      GLOAD16(g, l);
    }
    #pragma unroll
    for (int i2 = 0; i2 < 4; ++i2){
      const int u = w * 256 + i2 * 64 + lane;
      const int r = u >> 3, s = u & 7;
      const char* g = (const char*)B + (size_t)(n0 + r) * 512 + kb + ((s ^ (r & 7)) << 4);
      char* l = lds + 32768 + buf * 16384 + ((w * 256 + i2 * 64) << 4);
      GLOAD16(g, l);
    }
  };

  f32x4 acc[4][4];
  #pragma unroll
  for (int i = 0; i < 4; ++i)
    #pragma unroll
    for (int j = 0; j < 4; ++j){ f32x4 z = {0.f,0.f,0.f,0.f}; acc[i][j] = z; }

  const int wm = (w & 1) * 64, wn = (w >> 1) * 64;
  stage(0, 0);
  for (int it = 0; it < 4; ++it){
    const int buf = it & 1;
    if (it < 3) stage(it + 1, buf ^ 1);
    __syncthreads();
    const char* lA = lds + buf * 16384;
    const char* lB = lds + 32768 + buf * 16384;
    #pragma unroll
    for (int ks = 0; ks < 2; ++ks){
      half8 a[4], b[4];
      const int s = ks * 4 + lh;
      #pragma unroll
      for (int mt = 0; mt < 4; ++mt){
        const int r = wm + mt * 16 + lr;
        a[mt] = *(const half8*)(lA + r * 128 + ((s ^ (r & 7)) << 4));
      }
      #pragma unroll
      for (int nt = 0; nt < 4; ++nt){
        const int r = wn + nt * 16 + lr;
        b[nt] = *(const half8*)(lB + r * 128 + ((s ^ (r & 7)) << 4));
      }
      #pragma unroll
      for (int mt = 0; mt < 4; ++mt)
        #pragma unroll
        for (int nt = 0; nt < 4; ++nt)
          acc[mt][nt] = __builtin_amdgcn_mfma_f32_16x16x32_f16(a[mt], b[nt], acc[mt][nt], 0, 0, 0);
    }
    __syncthreads();
  }
  #pragma unroll
  for (int mt = 0; mt < 4; ++mt)
    #pragma unroll
    for (int nt = 0; nt < 4; ++nt)
      #pragma unroll
      for (int r = 0; r < 4; ++r){
        const size_t row = m0 + wm + mt * 16 + lh * 4 + r;
        const int col = n0 + wn + nt * 16 + lr;
        xg[row * NG + col] = (_Float16)acc[mt][nt][r];
      }
}

// ---------------------------------------------------------------------------
// Persistent recurrent kernel, 2-substep (A/B) pipelined.
// 16 batch-groups x 16 rows; substep A = rows 0..8, B = rows 8..16 (own flags).
// 16 col-WGs x 32 cols; w_hh slice [128 gate rows][512] fp16 in LDS (128KB).
// While substep B computes, substep A's publish latency is hidden.
__global__ __launch_bounds__(512) void k_lstm(const _Float16* __restrict__ xg,
    const float* __restrict__ w_hh, const float* __restrict__ b_ih,
    const float* __restrict__ b_hh, u16* __restrict__ hbuf_g,
    u32* __restrict__ cnt, float* __restrict__ out){
  extern __shared__ char lds[];
  char* Wl  = lds;                        // 131072 B
  char* hbA = lds + 131072;               //   8192 B (8 rows x 1KB, swizzled)
  char* hbB = lds + 139264;               //   8192 B
  float* gbA = (float*)(lds + 147456);    //   4096 B [8 strips][8 brow][16]
  float* gbB = (float*)(lds + 151552);    //   4096 B

  const int tid = threadIdx.x, w = tid >> 6, lane = tid & 63;
  const int lr = lane & 15, lh = lane >> 4;
  const int gb = blockIdx.x >> 4, gn = blockIdx.x & 15;
  const int b0 = gb * 16, j0 = gn * 32;
  u32* flagA = cnt + gb * 128;
  u32* flagB = flagA + 64;

  // ---- w_hh slice fp32 -> fp16 -> LDS (once), XOR-swizzled 16B units
  for (int rep = 0; rep < 16; ++rep){
    const int u = rep * 512 + tid;        // 0..8191 units
    const int row = u >> 6, u0 = u & 63;
    const int grow = ((row >> 5) << 9) + j0 + (row & 31);
    const float* src = w_hh + (size_t)grow * HH + u0 * 8;
    const float4 va = *(const float4*)src;
    const float4 vb = *(const float4*)(src + 4);
    union { _Float16 h[8]; u32x4 v; } p;
    p.h[0] = (_Float16)va.x; p.h[1] = (_Float16)va.y;
    p.h[2] = (_Float16)va.z; p.h[3] = (_Float16)va.w;
    p.h[4] = (_Float16)vb.x; p.h[5] = (_Float16)vb.y;
    p.h[6] = (_Float16)vb.z; p.h[7] = (_Float16)vb.w;
    *(u32x4*)(Wl + row * 1024 + ((u0 ^ (row & 7)) << 4)) = p.v;
  }
  const int sub  = tid >> 8;             // 0 = A half, 1 = B half
  const int brow = (tid & 255) >> 5;     // 0..7
  const int jj   = tid & 31;
  float bias_[4];
  #pragma unroll
  for (int q = 0; q < 4; ++q) bias_[q] = b_ih[q * HH + j0 + jj] + b_hh[q * HH + j0 + jj];
  float c = 0.f;
  const int sr = tid >> 6, su = tid & 63;                 // stage unit (8 rows x 64)
  const int slds = sr * 1024 + ((su ^ (sr & 7)) << 4);
  __syncthreads();

  for (int t = 0; t < TT; ++t){
    // xg prefetch for this thread's cell (issued before any waiting)
    const _Float16* xt = xg + (size_t)t * (BB * NG) + (size_t)(b0 + sub * 8 + brow) * NG + j0 + jj;
    u32 xv0, xv1, xv2, xv3;
    asm volatile(
      "global_load_ushort %0, %4, off\n\t"
      "global_load_ushort %1, %5, off\n\t"
      "global_load_ushort %2, %6, off\n\t"
      "global_load_ushort %3, %7, off"
      : "=&v"(xv0), "=&v"(xv1), "=&v"(xv2), "=&v"(xv3)
      : "v"(xt), "v"(xt + HH), "v"(xt + 2 * HH), "v"(xt + 3 * HH)
      : "memory");

    #pragma unroll
    for (int ss = 0; ss < 2; ++ss){
      u32* flag = ss ? flagB : flagA;
      char* hb = ss ? hbB : hbA;
      float* gbuf = ss ? gbB : gbA;
      if (t > 0){
        if (tid == 0){
          const u32 target = (u32)(16 * t);
          u32 v; int guard = 0;
          do {
            asm volatile("global_load_dword %0, %1, off sc0 sc1\n\t"
                         "s_waitcnt vmcnt(0)"
                         : "=v"(v) : "v"(flag) : "memory");
          } while (v < target && ++guard < (1 << 22));
        }
        __syncthreads();
        // stage h(t-1) substep rows into LDS (device-coherent)
        const char* gh = (const char*)hbuf_g + (size_t)((t - 1) & 1) * 262144
                       + (size_t)(b0 + ss * 8) * 1024 + sr * 1024 + su * 16;
        u32x4 hv;
        asm volatile("global_load_dwordx4 %0, %1, off sc0 sc1\n\t"
                     "s_waitcnt vmcnt(0)"
                     : "=v"(hv) : "v"(gh) : "memory");
        *(u32x4*)(hb + slds) = hv;
        __syncthreads();
        // gemm: wave w owns gate strip w (16 gate rows), K=512
        f32x4 ac0 = {0.f,0.f,0.f,0.f}, ac1 = {0.f,0.f,0.f,0.f};
        const int nr = w * 16 + lr;
        const int nbase = nr * 1024, nx = nr & 7, ax = lr & 7;
        const char* abase = hb + lr * 1024;  // rows 8..15 read benign garbage
        #pragma unroll
        for (int m = 0; m < 16; m += 2){
          const int s0 = m * 4 + lh, s1 = s0 + 4;
          const half8 a0 = *(const half8*)(abase + ((s0 ^ ax) << 4));
          const half8 bv0 = *(const half8*)(Wl + nbase + ((s0 ^ nx) << 4));
          ac0 = __builtin_amdgcn_mfma_f32_16x16x32_f16(a0, bv0, ac0, 0, 0, 0);
          const half8 a1 = *(const half8*)(abase + ((s1 ^ ax) << 4));
          const half8 bv1 = *(const half8*)(Wl + nbase + ((s1 ^ nx) << 4));
          ac1 = __builtin_amdgcn_mfma_f32_16x16x32_f16(a1, bv1, ac1, 0, 0, 0);
        }
        const f32x4 acs = ac0 + ac1;
        if (lh < 2){   // C rows 0..7 are the valid batch rows
          #pragma unroll
          for (int r = 0; r < 4; ++r)
            gbuf[(w * 8 + lh * 4 + r) * 16 + lr] = acs[r];
        }
        __syncthreads();
      }
      float cnew = c, hn = 0.f;
      if (sub == ss){
        asm volatile("s_waitcnt vmcnt(0)" ::: "memory");
        asm volatile("" : "+v"(xv0), "+v"(xv1), "+v"(xv2), "+v"(xv3));
        float g4[4];
        union { u32 u; _Float16 h[2]; } cv;
        cv.u = xv0; g4[0] = (float)cv.h[0] + bias_[0];
        cv.u = xv1; g4[1] = (float)cv.h[0] + bias_[1];
        cv.u = xv2; g4[2] = (float)cv.h[0] + bias_[2];
        cv.u = xv3; g4[3] = (float)cv.h[0] + bias_[3];
        if (t > 0){
          #pragma unroll
          for (int q = 0; q < 4; ++q)
            g4[q] += gbuf[((q * 2 + (jj >> 4)) * 8 + brow) * 16 + (jj & 15)];
        }
        const float i_ = 1.f / (1.f + __expf(-g4[0]));
        const float f_ = 1.f / (1.f + __expf(-g4[1]));
        const float ea = __expf(-2.f * fabsf(g4[2]));
        const float g_ = __builtin_copysignf((1.f - ea) / (1.f + ea), g4[2]);
        const float o_ = 1.f / (1.f + __expf(-g4[3]));
        cnew = f_ * c + i_ * g_;
        c = cnew;
        const float eb = __expf(-2.f * fabsf(cnew));
        const float th = __builtin_copysignf((1.f - eb) / (1.f + eb), cnew);
        hn = o_ * th;
        if (t < TT - 1){
          u16* ph = hbuf_g + (size_t)(t & 1) * (BB * HH)
                  + (size_t)(b0 + ss * 8 + brow) * HH + j0 + jj;
          const u32 hv16 = f2hbits(hn);
          asm volatile("global_store_short %0, %1, off sc0 sc1"
                       :: "v"(ph), "v"(hv16) : "memory");
        }
      }
      if (t < TT - 1){
        asm volatile("s_waitcnt vmcnt(0)" ::: "memory");
        __syncthreads();
        if (tid == 0)
          asm volatile("global_atomic_add %0, %1, off sc1" :: "v"(flag), "v"(1u) : "memory");
      }
      if (sub == ss)
        out[(size_t)t * (BB * HH) + (size_t)(b0 + ss * 8 + brow) * HH + j0 + jj] = c;
    }
  }
}

// ---------------------------------------------------------------------------
extern "C" void kernel_launch(void* const* d_in, const int* in_sizes, int n_in,
                              void* d_out, int out_size, void* d_ws, size_t ws_size,
                              hipStream_t stream){
  const float* x    = (const float*)d_in[0];
  const float* w_ih = (const float*)d_in[1];
  const float* w_hh = (const float*)d_in[2];
  const float* b_ih = (const float*)d_in[3];
  const float* b_hh = (const float*)d_in[4];
  float* out = (float*)d_out;
  char* ws = (char*)d_ws;

  const size_t o_xg  = 0;             // fp16 [400][256][2048] = 419,430,400 B
  const size_t o_xt  = 419430400;     // fp16 [400][256][256]  =  52,428,800 B
  const size_t o_wp  = 471859200;     // fp16 [2048][256]      =   1,048,576 B
  const size_t o_h   = 472907776;     // fp16 [2][256][512]    =     524,288 B
  const size_t o_cnt = 473432064;     // flags 16 groups x 512B =      8,192 B
  const size_t need  = 473440256;
  if (ws_size < need) return;

  _Float16* xg = (_Float16*)(ws + o_xg);
  u16* xt  = (u16*)(ws + o_xt);
  u16* wp  = (u16*)(ws + o_wp);
  u16* hb  = (u16*)(ws + o_h);
  u32* cnt = (u32*)(ws + o_cnt);

  hipMemsetAsync(cnt, 0, 8192, stream);
  hipLaunchKernelGGL(k_prep_x, dim3(51200), dim3(256), 0, stream, x, xt);
  hipLaunchKernelGGL(k_prep_w, dim3(512), dim3(256), 0, stream, w_ih, wp);
  hipLaunchKernelGGL(k_gemm_xg, dim3(12800), dim3(256), 0, stream, xt, wp, xg);
  hipLaunchKernelGGL(k_lstm, dim3(256), dim3(512), 155648, stream,
                     xg, w_hh, b_ih, b_hh, hb, cnt, out);
}

// Round 4
// 1816.559 us; speedup vs baseline: 1.2320x; 1.2320x over previous
//
#include <hip/hip_runtime.h>
#include <stdint.h>

#define TT 400
#define BB 256
#define II 256
#define HH 512
#define NG 2048  // 4*H

typedef __attribute__((ext_vector_type(8))) _Float16 half8;
typedef __attribute__((ext_vector_type(4))) float f32x4;
typedef __attribute__((ext_vector_type(4))) unsigned int u32x4;
typedef unsigned int u32;
typedef unsigned short u16;

static __device__ __forceinline__ u32 f2hbits(float f){
  union { _Float16 h; u16 u; } c; c.h = (_Float16)f; return (u32)c.u;
}

#define GLOAD16(gsrc, ldst) \
  __builtin_amdgcn_global_load_lds((const __attribute__((address_space(1))) void*)(gsrc), \
                                   (__attribute__((address_space(3))) void*)(ldst), 16, 0, 0)

// ---------------------------------------------------------------------------
// Transpose x[B][I][T] fp32 -> xT[t][b][i] fp16. Tile 32(i) x 16(t).
__global__ __launch_bounds__(256) void k_prep_x(const float* __restrict__ x,
                                                u16* __restrict__ xT){
  __shared__ float tile[32][17];
  const int bid = blockIdx.x;
  const int tb = bid % 25, ib = (bid / 25) & 7, b = bid / 200;
  const int t0 = tb * 16, i0 = ib * 32;
  const int tl = threadIdx.x & 15, il = threadIdx.x >> 4;
  tile[il][tl]      = x[(size_t)(b * II + i0 + il) * TT + t0 + tl];
  tile[il + 16][tl] = x[(size_t)(b * II + i0 + il + 16) * TT + t0 + tl];
  __syncthreads();
  const int t_l = threadIdx.x >> 4, ip = threadIdx.x & 15;
  const u32 pack = f2hbits(tile[2 * ip][t_l]) | (f2hbits(tile[2 * ip + 1][t_l]) << 16);
  *(u32*)(xT + ((size_t)(t0 + t_l) * BB + b) * II + i0 + 2 * ip) = pack;
}

// ---------------------------------------------------------------------------
// w_ih[2048][256] fp32 -> fp16.
__global__ __launch_bounds__(256) void k_prep_w(const float* __restrict__ w_ih,
                                                u16* __restrict__ Wp){
  const size_t idx = (size_t)blockIdx.x * 256 + threadIdx.x;  // 0..131071
  const float4 v = *(const float4*)(w_ih + idx * 4);
  uint2 o;
  o.x = f2hbits(v.x) | (f2hbits(v.y) << 16);
  o.y = f2hbits(v.z) | (f2hbits(v.w) << 16);
  *(uint2*)(Wp + idx * 4) = o;
}

// ---------------------------------------------------------------------------
// xg[M=102400][2048] fp16 = A[M][256] @ Wp[2048][256]^T, fp16 MFMA, K=256.
__global__ __launch_bounds__(256) void k_gemm_xg(const u16* __restrict__ A,
                                                 const u16* __restrict__ B,
                                                 _Float16* __restrict__ xg){
  __shared__ char lds[65536];  // A: buf*16384 ; B: 32768 + buf*16384
  const int tid = threadIdx.x, w = tid >> 6, lane = tid & 63;
  const int nb = blockIdx.x & 15, mb = blockIdx.x >> 4;
  const size_t m0 = (size_t)mb * 128;
  const int n0 = nb * 128;
  const int lr = lane & 15, lh = lane >> 4;

  auto stage = [&](int it, int buf){
    const size_t kb = (size_t)it * 128;  // 64 fp16 per k-step
    #pragma unroll
    for (int i2 = 0; i2 < 4; ++i2){
      const int u = w * 256 + i2 * 64 + lane;
      const int r = u >> 3, s = u & 7;
      const char* g = (const char*)A + (m0 + r) * 512 + kb + ((s ^ (r & 7)) << 4);
      char* l = lds + buf * 16384 + ((w * 256 + i2 * 64) << 4);
      GLOAD16(g, l);
    }
    #pragma unroll
    for (int i2 = 0; i2 < 4; ++i2){
      const int u = w * 256 + i2 * 64 + lane;
      const int r = u >> 3, s = u & 7;
      const char* g = (const char*)B + (size_t)(n0 + r) * 512 + kb + ((s ^ (r & 7)) << 4);
      char* l = lds + 32768 + buf * 16384 + ((w * 256 + i2 * 64) << 4);
      GLOAD16(g, l);
    }
  };

  f32x4 acc[4][4];
  #pragma unroll
  for (int i = 0; i < 4; ++i)
    #pragma unroll
    for (int j = 0; j < 4; ++j){ f32x4 z = {0.f,0.f,0.f,0.f}; acc[i][j] = z; }

  const int wm = (w & 1) * 64, wn = (w >> 1) * 64;
  stage(0, 0);
  for (int it = 0; it < 4; ++it){
    const int buf = it & 1;
    if (it < 3) stage(it + 1, buf ^ 1);
    __syncthreads();
    const char* lA = lds + buf * 16384;
    const char* lB = lds + 32768 + buf * 16384;
    #pragma unroll
    for (int ks = 0; ks < 2; ++ks){
      half8 a[4], b[4];
      const int s = ks * 4 + lh;
      #pragma unroll
      for (int mt = 0; mt < 4; ++mt){
        const int r = wm + mt * 16 + lr;
        a[mt] = *(const half8*)(lA + r * 128 + ((s ^ (r & 7)) << 4));
      }
      #pragma unroll
      for (int nt = 0; nt < 4; ++nt){
        const int r = wn + nt * 16 + lr;
        b[nt] = *(const half8*)(lB + r * 128 + ((s ^ (r & 7)) << 4));
      }
      #pragma unroll
      for (int mt = 0; mt < 4; ++mt)
        #pragma unroll
        for (int nt = 0; nt < 4; ++nt)
          acc[mt][nt] = __builtin_amdgcn_mfma_f32_16x16x32_f16(a[mt], b[nt], acc[mt][nt], 0, 0, 0);
    }
    __syncthreads();
  }
  #pragma unroll
  for (int mt = 0; mt < 4; ++mt)
    #pragma unroll
    for (int nt = 0; nt < 4; ++nt)
      #pragma unroll
      for (int r = 0; r < 4; ++r){
        const size_t row = m0 + wm + mt * 16 + lh * 4 + r;
        const int col = n0 + wn + nt * 16 + lr;
        xg[row * NG + col] = (_Float16)acc[mt][nt][r];
      }
}

// ---------------------------------------------------------------------------
// Persistent recurrent kernel — tag-in-data broadcast (no flags, no drains).
// 16 batch-groups x 16 col-WGs. WG owns 16 batch rows x 32 h-cols.
// htag[2][256][512] u32: low16 = fp16(h), high16 = step tag (t+1).
// Producers just store (sc0 sc1); consumers poll-load and retry stale units.
__global__ __launch_bounds__(512) void k_lstm(const _Float16* __restrict__ xg,
    const float* __restrict__ w_hh, const float* __restrict__ b_ih,
    const float* __restrict__ b_hh, u32* __restrict__ htag,
    float* __restrict__ out){
  extern __shared__ char lds[];
  char* Wl = lds;                         // 131072 B: [128 gate rows][512 fp16] swizzled
  char* hb = lds + 131072;                //  16384 B: h stage [16 rows][512 fp16] swizzled
  float* gbuf = (float*)(lds + 147456);   //   8192 B: [64 gate-rows][32 cols] fp32

  const int tid = threadIdx.x, w = tid >> 6, lane = tid & 63;
  const int lr = lane & 15, lh = lane >> 4;
  const int gb = blockIdx.x >> 4, gn = blockIdx.x & 15;
  const int b0 = gb * 16, j0 = gn * 32;

  // ---- w_hh slice fp32 -> fp16 -> LDS (once), XOR-swizzled 16B units
  for (int rep = 0; rep < 16; ++rep){
    const int u = rep * 512 + tid;        // 0..8191 units
    const int row = u >> 6, u0 = u & 63;
    const int grow = ((row >> 5) << 9) + j0 + (row & 31);
    const float* src = w_hh + (size_t)grow * HH + u0 * 8;
    const float4 va = *(const float4*)src;
    const float4 vb = *(const float4*)(src + 4);
    union { _Float16 h[8]; u32x4 v; } p;
    p.h[0] = (_Float16)va.x; p.h[1] = (_Float16)va.y;
    p.h[2] = (_Float16)va.z; p.h[3] = (_Float16)va.w;
    p.h[4] = (_Float16)vb.x; p.h[5] = (_Float16)vb.y;
    p.h[6] = (_Float16)vb.z; p.h[7] = (_Float16)vb.w;
    *(u32x4*)(Wl + row * 1024 + ((u0 ^ (row & 7)) << 4)) = p.v;
  }
  const int brow = tid >> 5;              // 0..15
  const int jj   = tid & 31;              // 0..31
  float bias_[4];
  #pragma unroll
  for (int q = 0; q < 4; ++q) bias_[q] = b_ih[q * HH + j0 + jj] + b_hh[q * HH + j0 + jj];
  float c = 0.f;
  const int q = w >> 1, jb = w & 1;

  // stage addressing: 1024 16B-units = [16 rows][64 units of 8 cols]; 2 units/thread
  const int u1 = tid, u2 = tid + 512;
  const int r1 = u1 >> 6, c1 = u1 & 63;
  const int r2 = u2 >> 6, c2 = u2 & 63;
  const size_t gof1 = (size_t)(b0 + r1) * 512 + c1 * 8;   // u32 index
  const size_t gof2 = (size_t)(b0 + r2) * 512 + c2 * 8;
  const int lof1 = r1 * 1024 + ((c1 ^ (r1 & 7)) << 4);
  const int lof2 = r2 * 1024 + ((c2 ^ (r2 & 7)) << 4);
  // producer store slot
  u32* pst0 = htag + (size_t)(b0 + brow) * 512 + (j0 + jj);
  __syncthreads();

  for (int t = 0; t < TT; ++t){
    // ---- xg prefetch (in flight under the poll)
    const _Float16* xt = xg + (size_t)t * (BB * NG) + (size_t)(b0 + brow) * NG + j0 + jj;
    u32 xv0, xv1, xv2, xv3;
    asm volatile(
      "global_load_ushort %0, %4, off\n\t"
      "global_load_ushort %1, %5, off\n\t"
      "global_load_ushort %2, %6, off\n\t"
      "global_load_ushort %3, %7, off"
      : "=&v"(xv0), "=&v"(xv1), "=&v"(xv2), "=&v"(xv3)
      : "v"(xt), "v"(xt + HH), "v"(xt + 2 * HH), "v"(xt + 3 * HH)
      : "memory");

    if (t > 0){
      // ---- poll-stage h[t-1]: tag must equal t
      const u32* gbase = htag + (size_t)((t - 1) & 1) * 131072;
      const u32* g1 = gbase + gof1;
      const u32* g2 = gbase + gof2;
      const u32 te = ((u32)t) << 16;
      u32x4 a0, a1, d0, d1;
      int need = 3, guard = 0;
      do {
        if (need & 1)
          asm volatile("global_load_dwordx4 %0, %2, off sc0 sc1\n\t"
                       "global_load_dwordx4 %1, %3, off sc0 sc1"
                       : "=&v"(a0), "=&v"(a1) : "v"(g1), "v"(g1 + 4) : "memory");
        if (need & 2)
          asm volatile("global_load_dwordx4 %0, %2, off sc0 sc1\n\t"
                       "global_load_dwordx4 %1, %3, off sc0 sc1"
                       : "=&v"(d0), "=&v"(d1) : "v"(g2), "v"(g2 + 4) : "memory");
        asm volatile("s_waitcnt vmcnt(0)" ::: "memory");
        if (need & 1){
          u32 m = (a0[0]^te)|(a0[1]^te)|(a0[2]^te)|(a0[3]^te)
                 |(a1[0]^te)|(a1[1]^te)|(a1[2]^te)|(a1[3]^te);
          if (!(m >> 16)) need &= ~1;
        }
        if (need & 2){
          u32 m = (d0[0]^te)|(d0[1]^te)|(d0[2]^te)|(d0[3]^te)
                 |(d1[0]^te)|(d1[1]^te)|(d1[2]^te)|(d1[3]^te);
          if (!(m >> 16)) need &= ~2;
        }
      } while (need && ++guard < (1 << 18));
      // strip tags, pack to fp16x8, write LDS
      u32x4 p1, p2;
      p1[0] = (a0[0] & 0xffffu) | (a0[1] << 16);
      p1[1] = (a0[2] & 0xffffu) | (a0[3] << 16);
      p1[2] = (a1[0] & 0xffffu) | (a1[1] << 16);
      p1[3] = (a1[2] & 0xffffu) | (a1[3] << 16);
      p2[0] = (d0[0] & 0xffffu) | (d0[1] << 16);
      p2[1] = (d0[2] & 0xffffu) | (d0[3] << 16);
      p2[2] = (d1[0] & 0xffffu) | (d1[1] << 16);
      p2[3] = (d1[2] & 0xffffu) | (d1[3] << 16);
      *(u32x4*)(hb + lof1) = p1;
      *(u32x4*)(hb + lof2) = p2;
      __syncthreads();                         // B1: stage complete
      // ---- gate GEMM: wave (q,jb) -> 16x16 C tile, K=512 (16 MFMA, 2 chains)
      f32x4 ac0 = {0.f,0.f,0.f,0.f}, ac1 = {0.f,0.f,0.f,0.f};
      const int nrow = q * 32 + jb * 16 + lr;
      const int nbase = nrow * 1024, nx = nrow & 7, ax = lr & 7;
      const char* abase = hb + lr * 1024;
      #pragma unroll
      for (int ks = 0; ks < 16; ks += 2){
        const int s0 = ks * 4 + lh, s1 = s0 + 4;
        const half8 av0 = *(const half8*)(abase + ((s0 ^ ax) << 4));
        const half8 bv0 = *(const half8*)(Wl + nbase + ((s0 ^ nx) << 4));
        ac0 = __builtin_amdgcn_mfma_f32_16x16x32_f16(av0, bv0, ac0, 0, 0, 0);
        const half8 av1 = *(const half8*)(abase + ((s1 ^ ax) << 4));
        const half8 bv1 = *(const half8*)(Wl + nbase + ((s1 ^ nx) << 4));
        ac1 = __builtin_amdgcn_mfma_f32_16x16x32_f16(av1, bv1, ac1, 0, 0, 0);
      }
      const f32x4 acs = ac0 + ac1;
      #pragma unroll
      for (int r = 0; r < 4; ++r)
        gbuf[(q * 16 + lh * 4 + r) * 32 + jb * 16 + lr] = acs[r];
      __syncthreads();                         // B2: gbuf ready
    }
    asm volatile("s_waitcnt vmcnt(0)" ::: "memory");
    asm volatile("" : "+v"(xv0), "+v"(xv1), "+v"(xv2), "+v"(xv3));

    // ---- pointwise LSTM cell
    float g4[4];
    {
      union { u32 u; _Float16 h[2]; } cv;
      cv.u = xv0; g4[0] = (float)cv.h[0] + bias_[0];
      cv.u = xv1; g4[1] = (float)cv.h[0] + bias_[1];
      cv.u = xv2; g4[2] = (float)cv.h[0] + bias_[2];
      cv.u = xv3; g4[3] = (float)cv.h[0] + bias_[3];
    }
    if (t > 0){
      #pragma unroll
      for (int qq = 0; qq < 4; ++qq) g4[qq] += gbuf[(qq * 16 + brow) * 32 + jj];
    }
    const float i_ = 1.f / (1.f + __expf(-g4[0]));
    const float f_ = 1.f / (1.f + __expf(-g4[1]));
    const float ea = __expf(-2.f * fabsf(g4[2]));
    const float g_ = __builtin_copysignf((1.f - ea) / (1.f + ea), g4[2]);
    const float o_ = 1.f / (1.f + __expf(-g4[3]));
    c = f_ * c + i_ * g_;
    const float eb = __expf(-2.f * fabsf(c));
    const float th = __builtin_copysignf((1.f - eb) / (1.f + eb), c);
    const float hn = o_ * th;

    if (t < TT - 1){
      // publish h[t]: tagged store, no drain, no flag
      u32* ph = pst0 + (size_t)(t & 1) * 131072;
      const u32 hv = f2hbits(hn) | ((u32)(t + 1) << 16);
      asm volatile("global_store_dword %0, %1, off sc0 sc1"
                   :: "v"(ph), "v"(hv) : "memory");
    }
    out[(size_t)t * (BB * HH) + (size_t)(b0 + brow) * HH + j0 + jj] = c;
  }
}

// ---------------------------------------------------------------------------
extern "C" void kernel_launch(void* const* d_in, const int* in_sizes, int n_in,
                              void* d_out, int out_size, void* d_ws, size_t ws_size,
                              hipStream_t stream){
  const float* x    = (const float*)d_in[0];
  const float* w_ih = (const float*)d_in[1];
  const float* w_hh = (const float*)d_in[2];
  const float* b_ih = (const float*)d_in[3];
  const float* b_hh = (const float*)d_in[4];
  float* out = (float*)d_out;
  char* ws = (char*)d_ws;

  const size_t o_xg  = 0;             // fp16 [400][256][2048] = 419,430,400 B
  const size_t o_xt  = 419430400;     // fp16 [400][256][256]  =  52,428,800 B
  const size_t o_wp  = 471859200;     // fp16 [2048][256]      =   1,048,576 B
  const size_t o_h   = 472907776;     // u32 [2][256][512]     =   1,048,576 B
  const size_t need  = 473956352;
  if (ws_size < need) return;

  _Float16* xg = (_Float16*)(ws + o_xg);
  u16* xt  = (u16*)(ws + o_xt);
  u16* wp  = (u16*)(ws + o_wp);
  u32* ht  = (u32*)(ws + o_h);

  hipLaunchKernelGGL(k_prep_x, dim3(51200), dim3(256), 0, stream, x, xt);
  hipLaunchKernelGGL(k_prep_w, dim3(512), dim3(256), 0, stream, w_ih, wp);
  hipLaunchKernelGGL(k_gemm_xg, dim3(12800), dim3(256), 0, stream, xt, wp, xg);
  hipLaunchKernelGGL(k_lstm, dim3(256), dim3(512), 155648, stream,
                     xg, w_hh, b_ih, b_hh, ht, out);
}